// Round 20
// baseline (92.176 us; speedup 1.0000x reference)
//
#include <hip/hip_runtime.h>
#include <hip/hip_bf16.h>

#define BB 4
#define CC 128
#define NN 4096
#define CK 32
#define L2E 1.442695040888963f

typedef __attribute__((ext_vector_type(8))) short short8v;
typedef __attribute__((ext_vector_type(4))) float float4v;

__device__ inline ushort f2bf(float f) {
    union { __hip_bfloat16 h; ushort u; } cv;
    cv.h = __float2bfloat16(f);
    return cv.u;
}
__device__ inline uint pk2(float lo, float hi) {
    return ((uint)f2bf(lo)) | ((uint)f2bf(hi) << 16);
}
__device__ __forceinline__ void gll16(const void* g, void* l) {
    __builtin_amdgcn_global_load_lds(
        (const __attribute__((address_space(1))) void*)g,
        (__attribute__((address_space(3))) void*)l, 16, 0, 0);
}
// volatile 16B global loads: cannot be sunk/reordered by the scheduler.
__device__ __forceinline__ short8v gload16(const ushort* addr) {
    short8v r;
    asm volatile("global_load_dwordx4 %0, %1, off"
                 : "=v"(r) : "v"(addr) : "memory");
    return r;
}
__device__ __forceinline__ float4v gload16f(const float* addr) {
    float4v r;
    asm volatile("global_load_dwordx4 %0, %1, off"
                 : "=v"(r) : "v"(addr) : "memory");
    return r;
}

// ---------------------------------------------------------------------------
// Kernel 0: weight prep.  Wcat[192][128] bf16 = {Wf*L2E; Wg; Wh*sgn},
// bias[192] fp32 = {bf*L2E; bg; bh*sgn}.
// ---------------------------------------------------------------------------
__global__ __launch_bounds__(512) void wprep_kernel(
    const float* __restrict__ Wf, const float* __restrict__ bf,
    const float* __restrict__ Wg, const float* __restrict__ bg,
    const float* __restrict__ Wh, const float* __restrict__ bh,
    const float* __restrict__ gamma,
    ushort* __restrict__ Wcat, float* __restrict__ bias_cat)
{
    const float sgn = (gamma[0] < 0.f) ? -1.f : 1.f;
    const int t = blockIdx.x * 512 + threadIdx.x;   // 0..24575
    const int o = t >> 7, c = t & 127;
    float w, scale;
    if (o < 32)      { w = Wf[o * 128 + c];        scale = L2E;  }
    else if (o < 64) { w = Wg[(o - 32) * 128 + c]; scale = 1.f;  }
    else             { w = Wh[(o - 64) * 128 + c]; scale = sgn;  }
    Wcat[t] = f2bf(w * scale);
    if (t < 192) {
        const float bv = (t < 32) ? bf[t] * L2E
                       : (t < 64) ? bg[t - 32]
                                  : bh[t - 64] * sgn;
        bias_cat[t] = bv;
    }
}

// ---------------------------------------------------------------------------
// Kernel 1: MFMA projections.  Grid (N/32, B) = 512 blocks, 512 thr.
// ---------------------------------------------------------------------------
__global__ __launch_bounds__(512) void proj_kernel(
    const float* __restrict__ x, const ushort* __restrict__ Wcat,
    const float* __restrict__ bias_cat,
    ushort* __restrict__ ft, ushort* __restrict__ gt, ushort* __restrict__ vh)
{
    __shared__ ushort xs[32][132];
    const int t  = threadIdx.x;
    const int n0 = blockIdx.x * 32;
    const int b  = blockIdx.y;
    const float* xb = x + (size_t)b * CC * NN;

    {
        const int nl = t & 31, cg = t >> 5;
        #pragma unroll
        for (int i = 0; i < 8; ++i) {
            const int c = cg + 16 * i;
            xs[nl][c] = f2bf(xb[(size_t)c * NN + n0 + nl]);
        }
    }
    __syncthreads();

    const int w   = t >> 6;
    const int l   = t & 63;
    const int g16 = l >> 4;
    const int l16 = l & 15;
    const int og  = w >> 1;
    const int nh  = w & 1;

    const float4v zf = {0.f, 0.f, 0.f, 0.f};
    float4v acc[3];
    #pragma unroll
    for (int tt = 0; tt < 3; ++tt) acc[tt] = zf;

    #pragma unroll
    for (int kt = 0; kt < 4; ++kt) {
        const short8v bfr = *reinterpret_cast<const short8v*>(
            &xs[nh * 16 + l16][32 * kt + 8 * g16]);
        #pragma unroll
        for (int tt = 0; tt < 3; ++tt) {
            const short8v afr = *reinterpret_cast<const short8v*>(
                &Wcat[(size_t)(48 * og + 16 * tt + l16) * 128 + 32 * kt + 8 * g16]);
            acc[tt] = __builtin_amdgcn_mfma_f32_16x16x32_bf16(afr, bfr, acc[tt], 0, 0, 0);
        }
    }

    const int n = n0 + nh * 16 + l16;
    #pragma unroll
    for (int tt = 0; tt < 3; ++tt) {
        const int ob = 48 * og + 16 * tt + 4 * g16;
        const float4 b4 = *reinterpret_cast<const float4*>(&bias_cat[ob]);
        const float v0 = acc[tt][0] + b4.x;
        const float v1 = acc[tt][1] + b4.y;
        const float v2 = acc[tt][2] + b4.z;
        const float v3 = acc[tt][3] + b4.w;
        if (ob < 32) {
            ushort4 pk;
            pk.x = f2bf(v0); pk.y = f2bf(v1); pk.z = f2bf(v2); pk.w = f2bf(v3);
            *reinterpret_cast<ushort4*>(&ft[((size_t)b * NN + n) * CK + ob]) = pk;
        } else if (ob < 64) {
            ushort4 pk;
            pk.x = f2bf(v0); pk.y = f2bf(v1); pk.z = f2bf(v2); pk.w = f2bf(v3);
            *reinterpret_cast<ushort4*>(&gt[((size_t)b * NN + n) * CK + (ob - 32)]) = pk;
        } else {
            const int c = ob - 64;
            vh[((size_t)b * CC + c + 0) * NN + n] = f2bf(v0);
            vh[((size_t)b * CC + c + 1) * NN + n] = f2bf(v1);
            vh[((size_t)b * CC + c + 2) * NN + n] = f2bf(v2);
            vh[((size_t)b * CC + c + 3) * NN + n] = f2bf(v3);
        }
    }
}

// ---------------------------------------------------------------------------
// Kernel 2: partial denominators D = sum_m 2^(S~) via MFMA.
// ---------------------------------------------------------------------------
__global__ __launch_bounds__(256) void pass1_kernel(
    const ushort* __restrict__ ft, const ushort* __restrict__ gt,
    float* __restrict__ Dpart)
{
    const int t   = threadIdx.x;
    const int w   = t >> 6;
    const int l   = t & 63;
    const int g16 = l >> 4;
    const int l16 = l & 15;
    const int n0  = blockIdx.x * 64;
    const int b   = blockIdx.y;
    const int mz  = blockIdx.z;

    const ushort* ftb = ft + (size_t)b * NN * CK;
    const ushort* gtb = gt + (size_t)b * NN * CK;

    const short8v afrag = *reinterpret_cast<const short8v*>(
        &ftb[(size_t)(n0 + 16 * w + l16) * CK + 8 * g16]);

    const float4v zf = {0.f, 0.f, 0.f, 0.f};
    float d0 = 0.f, d1 = 0.f, d2 = 0.f, d3 = 0.f;
    const int m0 = mz * 512;

    short8v bfA = *reinterpret_cast<const short8v*>(
        &gtb[(size_t)(m0 + l16) * CK + 8 * g16]);
    #pragma unroll 1
    for (int mt = 0; mt < 32; mt += 2) {
        const short8v bfB = *reinterpret_cast<const short8v*>(
            &gtb[(size_t)(m0 + (mt + 1) * 16 + l16) * CK + 8 * g16]);
        float4v s = __builtin_amdgcn_mfma_f32_16x16x32_bf16(afrag, bfA, zf, 0, 0, 0);
        d0 += __builtin_amdgcn_exp2f(s[0]); d1 += __builtin_amdgcn_exp2f(s[1]);
        d2 += __builtin_amdgcn_exp2f(s[2]); d3 += __builtin_amdgcn_exp2f(s[3]);
        bfA = *reinterpret_cast<const short8v*>(
            &gtb[(size_t)(m0 + (((mt + 2) & 31)) * 16 + l16) * CK + 8 * g16]);
        float4v s2 = __builtin_amdgcn_mfma_f32_16x16x32_bf16(afrag, bfB, zf, 0, 0, 0);
        d0 += __builtin_amdgcn_exp2f(s2[0]); d1 += __builtin_amdgcn_exp2f(s2[1]);
        d2 += __builtin_amdgcn_exp2f(s2[2]); d3 += __builtin_amdgcn_exp2f(s2[3]);
    }
    #pragma unroll
    for (int msk = 1; msk <= 8; msk <<= 1) {
        d0 += __shfl_xor(d0, msk);
        d1 += __shfl_xor(d1, msk);
        d2 += __shfl_xor(d2, msk);
        d3 += __shfl_xor(d3, msk);
    }
    if (l16 < 4) {
        const int n = n0 + 16 * w + 4 * g16 + l16;
        const float v = (l16 == 0) ? d0 : (l16 == 1) ? d1 : (l16 == 2) ? d2 : d3;
        Dpart[((size_t)b * NN + n) * 8 + mz] = v;
    }
}

// ---------------------------------------------------------------------------
// Kernel 3: sc[n] = |gamma| / D[n]   (applied to P inside pass2)
// ---------------------------------------------------------------------------
__global__ __launch_bounds__(256) void reduce_kernel(
    const float* __restrict__ Dpart, float* __restrict__ sc,
    const float* __restrict__ gamma)
{
    const int i = blockIdx.x * 256 + threadIdx.x;
    const float4 a4 = *reinterpret_cast<const float4*>(&Dpart[(size_t)i * 8]);
    const float4 b4 = *reinterpret_cast<const float4*>(&Dpart[(size_t)i * 8 + 4]);
    const float D = (a4.x + a4.y + a4.z + a4.w) + (b4.x + b4.y + b4.z + b4.w);
    sc[i] = fabsf(gamma[0]) / D;
}

// ---------------------------------------------------------------------------
// Kernel 4: sigma-permuted PV, r8-proven skeleton + volatile one-step-ahead
// prefetch.  BM=32, grid 512 (2 blocks/CU), 512 thr = 8 waves = (ch, nq in 4)
// -> 4 waves/SIMD; __launch_bounds__(512,4) -> 128 VGPR budget (the pinned
// prefetch fits; r18's 1024-thr 64-VGPR budget spilled it).  V staged
// wave-private dbuf via 4 x gll16/step; af + sc prefetched ONE STEP AHEAD via
// volatile asm; vmcnt(8) leaves only next-step ops in flight -> this step's
// operands all register/LDS-warm.  Zero barriers in the main loop.
// P = exp2(S~) * sc[n] packed bf16 (vscale kernel deleted).
// ---------------------------------------------------------------------------
#define WSTR  8192
#define VBUF  4096

__global__ __launch_bounds__(512, 4) void pass2_kernel(
    const ushort* __restrict__ ft, const ushort* __restrict__ gt,
    const ushort* __restrict__ vh, const float* __restrict__ sc,
    const float* __restrict__ x, float* __restrict__ out)
{
    __shared__ __align__(16) char smem[8 * WSTR];   // 64 KB

    const int t   = threadIdx.x;
    const int w   = t >> 6;
    const int l   = t & 63;
    const int g16 = l >> 4;
    const int l16 = l & 15;
    const int ch  = w & 1;     // c-half
    const int nq  = w >> 1;    // n-quarter

    const int bid = blockIdx.x;
    const int xcd = bid & 7;
    const int b   = xcd >> 1;
    const int m0  = ((bid >> 3) + 64 * (xcd & 1)) * 32;

    const ushort* ftb = ft + (size_t)b * NN * CK;
    const ushort* gtb = gt + (size_t)b * NN * CK;
    const ushort* vhb = vh + (size_t)b * CC * NN;
    const float*  scb = sc + (size_t)b * NN;

    char* wsm = smem + w * WSTR;

    short8v gfrag[2];
    #pragma unroll
    for (int tm = 0; tm < 2; ++tm)
        gfrag[tm] = *reinterpret_cast<const short8v*>(
            &gtb[(size_t)(m0 + 16 * tm + l16) * CK + 8 * g16]);

    const float4v zf = {0.f, 0.f, 0.f, 0.f};
    float4v acc[4][2];   // [tc][tm]
    #pragma unroll
    for (int tc = 0; tc < 4; ++tc)
        #pragma unroll
        for (int tm = 0; tm < 2; ++tm) acc[tc][tm] = zf;

    const int nbase = nq * 1024;
    const int rr = l >> 2, cp = l & 3;
    const ushort* afp = ftb + (size_t)l16 * CK + 8 * g16;   // + n*CK walks rows
    const float*  scp = scb + 4 * g16;                      // + n walks rows

#define STAGE(n0_, bo_) do {                                                   \
    _Pragma("unroll")                                                          \
    for (int j = 0; j < 4; ++j) {                                              \
        const int row = j * 16 + rr;                                           \
        gll16(vhb + (size_t)(64 * ch + row) * NN + (n0_)                       \
                  + (((2 * cp) ^ (row & 6)) << 2),                             \
              wsm + (bo_) + j * 1024);                                         \
    }                                                                          \
} while (0)

    // prologue: stage + prefetch step 0, drain all (incl. gfrag loads)
    STAGE(nbase, 0);
    short8v afA0 = gload16(afp + (size_t)nbase * CK);
    short8v afA1 = gload16(afp + (size_t)(nbase + 16) * CK);
    float4v scA0 = gload16f(scp + nbase);
    float4v scA1 = gload16f(scp + nbase + 16);
    asm volatile("s_waitcnt vmcnt(0)" ::: "memory");

    int bo = 0;
    #pragma unroll 1
    for (int st = 0; st < 32; ++st) {
        const int n1 = nbase + ((st + 1) & 31) * 32;   // wraps harmlessly at st=31

        // issue next step's staging + prefetch (volatile: order-pinned)
        STAGE(n1, bo ^ VBUF);
        short8v afB0 = gload16(afp + (size_t)n1 * CK);
        short8v afB1 = gload16(afp + (size_t)(n1 + 16) * CK);
        float4v scB0 = gload16f(scp + n1);
        float4v scB1 = gload16f(scp + n1 + 16);
        // 8 in flight (all next step's); this step's ops (issued last iter) drained.
        asm volatile("s_waitcnt vmcnt(8)" ::: "memory");

        const char* Vb = wsm + bo;

        // S~ rows: af0 -> n-local 4g16+r, af1 -> 16+4g16+r (matches scA0/scA1)
        union { uint u[4]; short8v s; } pf[2];
        #pragma unroll
        for (int tm = 0; tm < 2; ++tm) {
            float4v s0 = __builtin_amdgcn_mfma_f32_16x16x32_bf16(afA0, gfrag[tm], zf, 0, 0, 0);
            float4v s1 = __builtin_amdgcn_mfma_f32_16x16x32_bf16(afA1, gfrag[tm], zf, 0, 0, 0);
            pf[tm].u[0] = pk2(__builtin_amdgcn_exp2f(s0[0]) * scA0[0],
                              __builtin_amdgcn_exp2f(s0[1]) * scA0[1]);
            pf[tm].u[1] = pk2(__builtin_amdgcn_exp2f(s0[2]) * scA0[2],
                              __builtin_amdgcn_exp2f(s0[3]) * scA0[3]);
            pf[tm].u[2] = pk2(__builtin_amdgcn_exp2f(s1[0]) * scA1[0],
                              __builtin_amdgcn_exp2f(s1[1]) * scA1[1]);
            pf[tm].u[3] = pk2(__builtin_amdgcn_exp2f(s1[2]) * scA1[2],
                              __builtin_amdgcn_exp2f(s1[3]) * scA1[3]);
        }

        // PV: acc[c,m] += V[c, sigma(k)] * P[sigma(k), m]  (c-half = ch)
        #pragma unroll
        for (int tc = 0; tc < 4; ++tc) {
            const int cl = 16 * tc + l16;
            const uint2 va  = *reinterpret_cast<const uint2*>(
                Vb + cl * 64 + 8 * (g16 ^ (cl & 6)));
            const uint2 vb2 = *reinterpret_cast<const uint2*>(
                Vb + cl * 64 + 8 * ((4 + g16) ^ (cl & 6)));
            union { uint u[4]; short8v s; } av;
            av.u[0] = va.x;  av.u[1] = va.y;
            av.u[2] = vb2.x; av.u[3] = vb2.y;
            acc[tc][0] = __builtin_amdgcn_mfma_f32_16x16x32_bf16(av.s, pf[0].s, acc[tc][0], 0, 0, 0);
            acc[tc][1] = __builtin_amdgcn_mfma_f32_16x16x32_bf16(av.s, pf[1].s, acc[tc][1], 0, 0, 0);
        }

        afA0 = afB0; afA1 = afB1;
        scA0 = scB0; scA1 = scB1;
        bo ^= VBUF;
    }
#undef STAGE

    // ---- epilogue: cross-nq reduction (staging LDS reused; 48 KB) ----
    __syncthreads();   // drains outstanding loads/glls, then syncs
    float4v* rl = (float4v*)smem;
    if (nq != 0) {
        const int slot = (nq - 1) * 2 + ch;
        #pragma unroll
        for (int tc = 0; tc < 4; ++tc)
            #pragma unroll
            for (int tm = 0; tm < 2; ++tm)
                rl[(slot * 8 + tc * 2 + tm) * 64 + l] = acc[tc][tm];
    }
    __syncthreads();
    if (nq == 0) {
        const float* xb = x   + (size_t)b * CC * NN;
        float*       ob = out + (size_t)b * CC * NN;
        #pragma unroll
        for (int tc = 0; tc < 4; ++tc) {
            #pragma unroll
            for (int tm = 0; tm < 2; ++tm) {
                const int fi = tc * 2 + tm;
                float4v s = acc[tc][tm]
                          + rl[((ch) * 8 + fi) * 64 + l]
                          + rl[((2 + ch) * 8 + fi) * 64 + l]
                          + rl[((4 + ch) * 8 + fi) * 64 + l];
                const int cb = 64 * ch + 16 * tc + 4 * g16;
                const int m  = m0 + 16 * tm + l16;
                #pragma unroll
                for (int r = 0; r < 4; ++r) {
                    const size_t idx = (size_t)(cb + r) * NN + m;
                    ob[idx] = s[r] + xb[idx];
                }
            }
        }
    }
}

// ---------------------------------------------------------------------------
extern "C" void kernel_launch(void* const* d_in, const int* in_sizes, int n_in,
                              void* d_out, int out_size, void* d_ws, size_t ws_size,
                              hipStream_t stream)
{
    const float* x     = (const float*)d_in[0];
    const float* Wf    = (const float*)d_in[1];
    const float* bf    = (const float*)d_in[2];
    const float* Wg    = (const float*)d_in[3];
    const float* bg    = (const float*)d_in[4];
    const float* Wh    = (const float*)d_in[5];
    const float* bh    = (const float*)d_in[6];
    const float* gamma = (const float*)d_in[7];

    ushort* ft = (ushort*)d_ws;                    // [B][N][CK] bf16 (x log2e)
    ushort* gt = ft + (size_t)BB * NN * CK;        // [B][N][CK] bf16
    ushort* vh = gt + (size_t)BB * NN * CK;        // [B][C][N]  bf16 (sign folded)
    float* Dpart = (float*)(vh + (size_t)BB * CC * NN);  // [B*N][8]
    float* sc    = Dpart + (size_t)BB * NN * 8;          // [B*N] |g|/D
    float* bias_cat = sc + (size_t)BB * NN;              // [192]
    ushort* Wcat = (ushort*)(bias_cat + 192);            // [192][128] bf16

    float* out = (float*)d_out;

    wprep_kernel<<<dim3(48), 512, 0, stream>>>(Wf, bf, Wg, bg, Wh, bh, gamma, Wcat, bias_cat);
    proj_kernel<<<dim3(NN / 32, BB), 512, 0, stream>>>(x, Wcat, bias_cat, ft, gt, vh);
    pass1_kernel<<<dim3(NN / 64, BB, 8), 256, 0, stream>>>(ft, gt, Dpart);
    reduce_kernel<<<dim3(BB * NN / 256), 256, 0, stream>>>(Dpart, sc, gamma);
    pass2_kernel<<<dim3(512), 512, 0, stream>>>(ft, gt, vh, sc, x, out);
}